// Round 5
// baseline (5803.350 us; speedup 1.0000x reference)
//
#include <hip/hip_runtime.h>

// LSTM last-h + LeakyReLU(0.3). B=128 T=1024 F=64 H=256.
// R22: R21 with a NON-DCE-ABLE LDS occupancy forcer.
// R21 post-mortem: LDS_Block_Size stayed 1536 -- the 84KB pad was
// store-only, so it was dead-code-eliminated and the occupancy model
// never changed; VGPR cap stayed 64 and weights kept reloading.
// Evidence for the theory itself: R17 (152KB LDS) compiled with the
// 128-VGPR budget (1 WG/CU plan). Fix here: the pad tail is READ under
// a runtime-opaque guard (bias-dependent, never true, unprovable) and
// the loaded value is stored to out -- a load feeding a potential
// global store cannot be eliminated, so the 85KB allocation must stick.
// 2x85KB > 160KB -> 1 WG/CU -> 4 waves/EU -> VGPR budget 128 -> the
// 80-VGPR pinned weight array stays register-resident.
// Structure (unchanged from R18):
//  - 256 WGs = 128 rows x 2 col-groups; clique = 2 WGs (bids r, r+128
//    -> same XCD mod 8), 1 partner.
//  - 1024 thr = 512 cols x 2 k-halves; 20 uint4 words = 80 fdot2/thread
//    /step, weights in 80 VGPRs loaded once (asm-pinned).
//  - col c = j*4+g: 4 gates of h-col j in one wave; gates via shfl_down.
//  - gather wave (15) polls AFTER its early dots: B1 at max(D_early,RTT).
//  - 2 barriers/step.

#define BATCH   128
#define TSTEPS  1024
#define FDIM    64
#define HDIM    256
#define G4      1024
#define NWORDS  20                               // uint4 words per thread
#define W4S_U4     (2 * NWORDS * 1024)           // 40960 uint4
#define W4S_BYTES  (W4S_U4 * 16)                 // 655360
#define EX_OFF     W4S_BYTES
#define EX_SLOTS   (BATCH * 2 * 2 * 64)          // 32768 uint64 slots
#define EX_BYTES   (EX_SLOTS * 8)                // 262144
#define WS_NEED    (EX_OFF + EX_BYTES)           // 917504 (same as R17)

#define LDS_U4  5328                             // 85248 B total LDS

typedef _Float16 half2_t __attribute__((ext_vector_type(2)));
typedef unsigned u32x4 __attribute__((ext_vector_type(4)));

__device__ __forceinline__ half2_t as_h2(unsigned u) {
    union { unsigned u; half2_t h; } c; c.u = u; return c.h;
}
__device__ __forceinline__ float fdot2f(half2_t a, half2_t b, float c) {
    return __builtin_amdgcn_fdot2(a, b, c, false);
}
__device__ __forceinline__ unsigned pack2(float a, float b) {
    union { _Float16 h[2]; unsigned u; } c;
    c.h[0] = (_Float16)a; c.h[1] = (_Float16)b; return c.u;
}

#define DOT4(a0,a1,a2,a3,xv,wv) \
    a0 = fdot2f(as_h2((xv).x), as_h2((wv).x), a0); \
    a1 = fdot2f(as_h2((xv).y), as_h2((wv).y), a1); \
    a2 = fdot2f(as_h2((xv).z), as_h2((wv).z), a2); \
    a3 = fdot2f(as_h2((xv).w), as_h2((wv).w), a3);

// w4s layout: [cg][wi 0..19][tid 0..1023] uint4 -- coalesced reg-load.
// thread tid: c = tid>>1 (c = j*4+g), kh = tid&1; word w = 2*wi+kh;
// dword d covers k' = 8w+2d, 8w+2d+1.
__global__ void pack_weights2(const float* __restrict__ wk,
                              const float* __restrict__ wr,
                              unsigned* __restrict__ w4s) {
    int idx = blockIdx.x * blockDim.x + threadIdx.x;
    if (idx >= W4S_U4 * 4) return;
    int u4 = idx >> 2, d = idx & 3;
    int tid = u4 & 1023;
    int wi  = (u4 >> 10) % NWORDS;
    int cg  = u4 / (NWORDS * 1024);
    int c = tid >> 1, kh = tid & 1;
    int j = c >> 2, g = c & 3;
    int gcol = g * 256 + cg * 128 + j;
    int w = 2 * wi + kh;
    float v[2];
    #pragma unroll
    for (int s2 = 0; s2 < 2; ++s2) {
        int kp = 8 * w + 2 * d + s2;
        if (kp < 64)       v[s2] = wk[kp * G4 + gcol];
        else if (kp < 192) v[s2] = wr[(cg * 128 + (kp - 64)) * G4 + gcol];
        else               v[s2] = wr[((cg ^ 1) * 128 + (kp - 192)) * G4 + gcol];
    }
    w4s[idx] = pack2(v[0], v[1]);
}

__global__ __attribute__((amdgpu_flat_work_group_size(1024, 1024),
                          amdgpu_waves_per_eu(4, 4)))
void lstm_2way(
    const float* __restrict__ inputs,
    const uint4* __restrict__ w4s,
    const float* __restrict__ bias,
    unsigned long long* __restrict__ ex2,
    float* __restrict__ out)
{
    // One 85KB LDS block. First 80 uint4 = xh double buffer:
    //   dwords [0..31] x_t f16-pairs, [32..95] own h, [96..159] partner h.
    // Tail = occupancy forcer, READ under an opaque guard (not DCE-able).
    __shared__ uint4 lds_all[LDS_U4];
    uint4 (*xh4)[40] = reinterpret_cast<uint4 (*)[40]>(&lds_all[0]);

    const int bid = blockIdx.x;
    const int cg  = bid >> 7;
    const int row = bid & 127;
    const int tid = threadIdx.x;
    const int kh  = tid & 1;
    const int j   = tid >> 3;        // h-col (local) for gate lanes

    // ---- weights -> 80 VGPRs, ONCE; asm use-point prevents re-load ----
    u32x4 Wv[NWORDS];
    {
        const u32x4* __restrict__ Wp =
            (const u32x4*)(w4s + (size_t)cg * NWORDS * 1024 + tid);
        #pragma unroll
        for (int wi = 0; wi < NWORDS; ++wi) {
            Wv[wi] = Wp[wi * 1024];
            asm volatile("" : "+v"(Wv[wi]));
        }
    }

    const float* __restrict__ xrow = inputs + (size_t)row * TSTEPS * FDIM;

    // init xh[0]: x_0 packed, h_0 = 0 (own + partner regions)
    if (tid < 32) {
        float2 x2 = ((const float2*)xrow)[tid];
        ((unsigned*)&xh4[0][0])[tid] = pack2(x2.x, x2.y);
    } else if (tid < 160) {
        ((unsigned*)&xh4[0][0])[tid] = 0u;
    }

    const float bi = bias[        cg * 128 + j];
    const float bf = bias[256   + cg * 128 + j];
    const float bc = bias[512   + cg * 128 + j];
    const float bo = bias[768   + cg * 128 + j];

    // Occupancy forcer keep-alive: a READ of the pad feeding a global
    // store under a bias-dependent (never-true, unprovable) guard.
    if (bi + bf + bc + bo > 4e30f)
        out[tid] = ((const float*)&lds_all[80])[tid];

    unsigned long long* const pubB = ex2 + (size_t)((row * 2 + cg)       * 2) * 64;
    unsigned long long* const polB = ex2 + (size_t)((row * 2 + (cg ^ 1)) * 2) * 64;

    const bool gatherer = (tid >= 960);          // wave 15, lane gl -> slot gl
    const int  gl = tid - 960;
    const bool stager = (tid >= 512 && tid < 544);
    const int  sx = tid - 512;

    float cstate = 0.0f;
    __syncthreads();

    for (int s = 0; s < TSTEPS; ++s) {
        const int cp = s & 1, ncp = cp ^ 1;
        const uint4* __restrict__ Xk = &xh4[cp][0] + kh;   // word w = 2*wi+kh

        // speculative poll issue (flies under early dots)
        unsigned long long* const psrc = polB + (size_t)(s & 1) * 64 + gl;
        unsigned long long pv = 0;
        if (gatherer && s > 0)
            pv = __hip_atomic_load(psrc, __ATOMIC_RELAXED, __HIP_MEMORY_SCOPE_AGENT);

        // x_{s+1} prefetch (vmcnt wait lands after the dots)
        float2 xnext = make_float2(0.f, 0.f);
        if (stager && s + 1 < TSTEPS)
            xnext = ((const float2*)(xrow + (s + 1) * FDIM))[sx];

        float A0 = 0.f, A1 = 0.f, A2 = 0.f, A3 = 0.f;

        // early dots: x + own h (12 words, reg weights, LDS broadcast reads)
        #pragma unroll
        for (int wi = 0; wi < 12; ++wi) {
            uint4 xv = Xk[2 * wi];
            DOT4(A0, A1, A2, A3, xv, Wv[wi]);
        }

        // gather AFTER early dots: B1 releases at max(D_early, RTT)
        if (gatherer && s > 0) {
            int it = 0;
            while ((unsigned)(pv >> 32) != (unsigned)s && ++it < (1 << 22))
                pv = __hip_atomic_load(psrc, __ATOMIC_RELAXED,
                                       __HIP_MEMORY_SCOPE_AGENT);
            unsigned pdw = ((unsigned)(pv >> 32) == (unsigned)s) ? (unsigned)pv : 0u;
            ((unsigned*)&xh4[cp][24])[gl] = pdw;           // dw 96+gl
        }
        __syncthreads();                                   // B1

        // late dots: partner h (8 words)
        #pragma unroll
        for (int wi = 12; wi < 20; ++wi) {
            uint4 xv = Xk[2 * wi];
            DOT4(A0, A1, A2, A3, xv, Wv[wi]);
        }

        // reduce kh halves, then gather the 4 gates in-wave
        float z = (A0 + A1) + (A2 + A3);
        z += __shfl_xor(z, 1);
        const float zfv = __shfl_down(z, 2);
        const float zcv = __shfl_down(z, 4);
        const float zov = __shfl_down(z, 6);

        // gate math (all lanes execute; only tid&7==0 lanes hold real values)
        const float zi = z   + bi;
        const float zf = zfv + bf;
        const float zc = zcv + bc;
        const float zo = zov + bo;
        const float ig = 1.0f / (1.0f + __expf(-zi));
        const float fg = 1.0f / (1.0f + __expf(-zf));
        const float gg = 1.0f - 2.0f / (__expf(2.0f * zc) + 1.0f);
        const float og = 1.0f / (1.0f + __expf(-zo));
        cstate = fmaf(fg, cstate, ig * gg);
        const float hn = og * (1.0f - 2.0f / (__expf(2.0f * cstate) + 1.0f));
        const float hno = __shfl_down(hn, 8);              // h_{j+1}

        if ((tid & 7) == 0) {
            if (s == TSTEPS - 1) {
                const float h = hn;
                out[row * HDIM + cg * 128 + j] = (h >= 0.0f) ? h : 0.3f * h;
            } else if ((tid & 15) == 0) {                  // even j
                const unsigned u = pack2(hn, hno);
                const unsigned long long pvw =
                    ((unsigned long long)(unsigned)(s + 1) << 32) |
                    (unsigned long long)u;
                __hip_atomic_store(pubB + (size_t)((s + 1) & 1) * 64 + (j >> 1),
                                   pvw, __ATOMIC_RELAXED,
                                   __HIP_MEMORY_SCOPE_AGENT);
                ((unsigned*)&xh4[ncp][8])[j >> 1] = u;     // own h, dw 32+j/2
            }
        }
        if (stager && s + 1 < TSTEPS)
            ((unsigned*)&xh4[ncp][0])[sx] = pack2(xnext.x, xnext.y);
        __syncthreads();                                   // B3
    }
}

// ---- fallback (needs no ws): round-1 kernel ----
__global__ __launch_bounds__(HDIM) void lstm_fused(
    const float* __restrict__ inputs, const float* __restrict__ wk,
    const float* __restrict__ wr, const float* __restrict__ bias,
    float* __restrict__ out)
{
    const int b = blockIdx.x;
    const int t = threadIdx.x;
    __shared__ float hs[2][HDIM];
    __shared__ float xs[2][FDIM];
    const float* __restrict__ xin = inputs + (size_t)b * TSTEPS * FDIM;
    float c = 0.0f;
    hs[0][t] = 0.0f;
    if (t < FDIM) xs[0][t] = xin[t];
    const float bi = bias[t];
    const float bf = bias[HDIM + t];
    const float bc = bias[2 * HDIM + t];
    const float bo = bias[3 * HDIM + t];
    __syncthreads();
    int p = 0;
    for (int step = 0; step < TSTEPS; ++step) {
        float zi = bi, zf = bf, zc = bc, zo = bo;
        const float* xsp = xs[p];
        const float* hsp = hs[p];
        #pragma unroll 8
        for (int f = 0; f < FDIM; ++f) {
            const float xv = xsp[f];
            const float* Kf = wk + f * G4 + t;
            zi = fmaf(xv, Kf[0], zi);
            zf = fmaf(xv, Kf[HDIM], zf);
            zc = fmaf(xv, Kf[2 * HDIM], zc);
            zo = fmaf(xv, Kf[3 * HDIM], zo);
        }
        #pragma unroll 8
        for (int k = 0; k < HDIM; ++k) {
            const float hv = hsp[k];
            const float* Rk = wr + k * G4 + t;
            zi = fmaf(hv, Rk[0], zi);
            zf = fmaf(hv, Rk[HDIM], zf);
            zc = fmaf(hv, Rk[2 * HDIM], zc);
            zo = fmaf(hv, Rk[3 * HDIM], zo);
        }
        const float ig = 1.0f / (1.0f + __expf(-zi));
        const float fg = 1.0f / (1.0f + __expf(-zf));
        const float gg = 1.0f - 2.0f / (__expf(2.0f * zc) + 1.0f);
        const float og = 1.0f / (1.0f + __expf(-zo));
        c = fmaf(fg, c, ig * gg);
        const float hn = og * (1.0f - 2.0f / (__expf(2.0f * c) + 1.0f));
        float xnext = 0.0f;
        if (t < FDIM && step + 1 < TSTEPS) xnext = xin[(step + 1) * FDIM + t];
        hs[p ^ 1][t] = hn;
        if (t < FDIM) xs[p ^ 1][t] = xnext;
        __syncthreads();
        p ^= 1;
    }
    const float h = hs[p][t];
    out[b * HDIM + t] = (h >= 0.0f) ? h : 0.3f * h;
}

extern "C" void kernel_launch(void* const* d_in, const int* in_sizes, int n_in,
                              void* d_out, int out_size, void* d_ws, size_t ws_size,
                              hipStream_t stream) {
    const float* inputs = (const float*)d_in[0];
    const float* wk     = (const float*)d_in[1];
    const float* wr     = (const float*)d_in[2];
    const float* bias   = (const float*)d_in[3];
    float* out          = (float*)d_out;

    if (ws_size >= (size_t)WS_NEED) {
        unsigned* w4s = (unsigned*)d_ws;
        unsigned long long* ex2 = (unsigned long long*)((char*)d_ws + EX_OFF);
        hipMemsetAsync(ex2, 0xFF, EX_BYTES, stream);   // all tags invalid
        int ndw = W4S_U4 * 4;
        pack_weights2<<<dim3((ndw + 255) / 256), dim3(256), 0, stream>>>(wk, wr, w4s);
        lstm_2way<<<dim3(256), dim3(1024), 0, stream>>>(
            inputs, (const uint4*)w4s, bias, ex2, out);
    } else {
        lstm_fused<<<dim3(BATCH), dim3(HDIM), 0, stream>>>(inputs, wk, wr, bias, out);
    }
}

// Round 6
// 1783.752 us; speedup vs baseline: 3.2535x; 3.2535x over previous
//
#include <hip/hip_runtime.h>

// LSTM last-h + LeakyReLU(0.3). B=128 T=1024 F=64 H=256.
// R23: R17 base (proven 1790us) + two targeted changes inside the
// 64-VGPR cap:
//  (a) gather poll moved AFTER early dots (speculative load at top):
//      B1 path = max(D_early, RTT-remainder), not RTT + D_early.
//  (b) 2 of 9 LDS weight words pinned in registers (8 VGPRs, 52->~60):
//      LDS weight reads 9 -> 7 words/thread/step (147KB -> 115KB/CU).
// R18-R22 lessons recorded: the RA refuses >64 VGPRs for this kernel
// shape regardless of __launch_bounds__(1024,4), waves_per_eu(4,4), or
// LDS-forced 1-WG/CU (R22 proved LDS=85KB + VGPR still 64); the pinned
// 80-VGPR weight array spills to scratch (~5800cy/step L2 thrash,
// 5.4-5.8ms). Full register residency unreachable -> incremental only.
// In-wave gates (R18) rejected by arithmetic: +~400cy/step VALU issue
// on 16 waves to remove a ~150-250cy 2-wave serial tail.

#define BATCH   128
#define TSTEPS  1024
#define FDIM    64
#define HDIM    256
#define G4      1024
#define NW      40
#define NCOLS   256
#define NLDSW   28                               // 7 words/thread in LDS
#define NROWS   2
#define W4S_U4     (4 * NW * NCOLS)              // 40960 uint4
#define W4S_BYTES  (W4S_U4 * 16)                 // 655360
#define EX_OFF     W4S_BYTES
#define EX_SLOTS   (64 * 4 * 2 * 2 * 32)         // 32768 uint64 slots
#define EX_BYTES   (EX_SLOTS * 8)                // 262144
#define WS_NEED    (EX_OFF + EX_BYTES)           // 917504 (R13-proven)

typedef _Float16 half2_t __attribute__((ext_vector_type(2)));
typedef unsigned u32x4 __attribute__((ext_vector_type(4)));

__device__ __forceinline__ half2_t as_h2(unsigned u) {
    union { unsigned u; half2_t h; } c; c.u = u; return c.h;
}
__device__ __forceinline__ float fdot2f(half2_t a, half2_t b, float c) {
    return __builtin_amdgcn_fdot2(a, b, c, false);
}
__device__ __forceinline__ unsigned pack2(float a, float b) {
    union { _Float16 h[2]; unsigned u; } c;
    c.h[0] = (_Float16)a; c.h[1] = (_Float16)b; return c.u;
}

#define DOT4(a0,a1,a2,a3,xv,wv) \
    a0 = fdot2f(as_h2((xv).x), as_h2((wv).x), a0); \
    a1 = fdot2f(as_h2((xv).y), as_h2((wv).y), a1); \
    a2 = fdot2f(as_h2((xv).z), as_h2((wv).z), a2); \
    a3 = fdot2f(as_h2((xv).w), as_h2((wv).w), a3);

// pack into w4s[cg][w 0..39][col 0..255][qd 0..3] dwords.  (R13-proven)
// k' per cg: 0..63 = x; 64..127 = h[cg*64+*]; 128+(m-1)*64+jj = h[((cg+m)&3)*64+jj]
__global__ void pack_weights4(const float* __restrict__ wk,
                              const float* __restrict__ wr,
                              unsigned* __restrict__ w4s) {
    int idx = blockIdx.x * blockDim.x + threadIdx.x;
    if (idx >= W4S_U4 * 4) return;
    int cg = idx / (NW * NCOLS * 4);
    int r  = idx % (NW * NCOLS * 4);
    int w  = r / (NCOLS * 4);
    int r2 = r % (NCOLS * 4);
    int l  = r2 >> 2;
    int qd = r2 & 3;
    int gcol = ((l >> 6) << 8) + cg * 64 + (l & 63);
    int kk = w * 4 + qd;
    float v[2];
    #pragma unroll
    for (int s2 = 0; s2 < 2; ++s2) {
        int kp = 2 * kk + s2;
        int k;
        if (kp < 64)        k = kp;
        else if (kp < 128)  k = 64 + cg * 64 + (kp - 64);
        else {
            int m = 1 + ((kp - 128) >> 6);
            int cgp = (cg + m) & 3;
            k = 64 + cgp * 64 + ((kp - 128) & 63);
        }
        v[s2] = (k < FDIM) ? wk[k * G4 + gcol] : wr[(k - FDIM) * G4 + gcol];
    }
    w4s[idx] = pack2(v[0], v[1]);
}

__global__ __launch_bounds__(1024) void lstm_4way(
    const float* __restrict__ inputs,
    const uint4* __restrict__ w4s,
    const float* __restrict__ bias,
    unsigned long long* __restrict__ ex2,
    float* __restrict__ out)
{
    __shared__ uint4    ldsW[(NLDSW / 4) * 1024];  // 7*1024 u4 = 114688 B
    __shared__ float    zs[NROWS][NCOLS];          // 2048 B
    __shared__ unsigned xh[2][NROWS][160];         // 2560 B  (total 119296)

    const int bid = blockIdx.x;
    const int pg  = bid & 63;                  // rows 2pg, 2pg+1
    const int cg  = bid >> 6;                  // col-group 0..3
    const int tid = threadIdx.x;
    const int col = ((tid >> 6) << 4) + (tid & 15);   // 0..255
    const int kq  = (tid >> 4) & 3;                    // k-quarter

    const uint4* __restrict__ Wcg = w4s + (size_t)cg * NW * NCOLS;

    // swizzled LDS fill (words 0..27): dst j = i*1024 + cb*64 + kk*16 + c
    //                                  <- src word w = 4i+kk, col = cb*16+c
    for (int j = tid; j < (NLDSW / 4) * 1024; j += 1024) {
        int i  = j >> 10;
        int cb = (j >> 6) & 15;
        int kk = (j >> 4) & 3;
        int c  = j & 15;
        ldsW[j] = Wcg[(4 * i + kk) * NCOLS + cb * 16 + c];
    }
    const int slotbase = ((tid >> 6) << 6) + (kq << 4) + (tid & 15);

    // ---- 2 weight words pinned in registers (words 28+kq, 32+kq) ----
    u32x4 Wp7, Wp8;
    {
        uint4 t7 = Wcg[(28 + kq) * NCOLS + col];
        uint4 t8 = Wcg[(32 + kq) * NCOLS + col];
        Wp7 = (u32x4){t7.x, t7.y, t7.z, t7.w};
        Wp8 = (u32x4){t8.x, t8.y, t8.z, t8.w};
        asm volatile("" : "+v"(Wp7));
        asm volatile("" : "+v"(Wp8));
    }

    const float* __restrict__ xr0 = inputs + (size_t)(2 * pg)     * TSTEPS * FDIM;
    const float* __restrict__ xr1 = inputs + (size_t)(2 * pg + 1) * TSTEPS * FDIM;

    // xh[0]: dw 0..31 = x_0 (f16 pairs), 32..159 = h_0 = 0
    if (tid < 64) {
        int r = tid >> 5, d = tid & 31;
        float2 x2 = ((const float2*)(r ? xr1 : xr0))[d];
        xh[0][r][d] = pack2(x2.x, x2.y);
    } else if (tid >= 64 && tid < 320) {
        int t2 = tid - 64;
        xh[0][t2 >> 7][32 + (t2 & 127)] = 0u;
    }

    // gate threads: tid<128, grow = tid>>6 (one wave per row), gj = tid&63
    const int grow = tid >> 6, gj = tid & 63;
    float bi = 0.f, bf = 0.f, bc = 0.f, bo = 0.f;
    if (tid < 128) {
        bi = bias[        cg * 64 + gj];
        bf = bias[256  + cg * 64 + gj];
        bc = bias[512  + cg * 64 + gj];
        bo = bias[768  + cg * 64 + gj];
    }

    float cstate = 0.0f;
    const int gt = tid - 128;          // gather threads: 128..319 (192)

    __syncthreads();

    for (int s = 0; s < TSTEPS; ++s) {
        const int cp = s & 1, ncp = cp ^ 1;
        const uint4* __restrict__ X0 = (const uint4*)&xh[cp][0][0];
        const uint4* __restrict__ X1 = (const uint4*)&xh[cp][1][0];

        // streamed weight word (w = 36+kq) -- issue first, flies under dots
        uint4 sv = Wcg[(36 + kq) * NCOLS + col];
        float2 xnext = make_float2(0.f, 0.f);
        if (tid >= 320 && tid < 384 && s + 1 < TSTEPS) {
            int t2 = tid - 320, r = t2 >> 5, d = t2 & 31;
            xnext = ((const float2*)((r ? xr1 : xr0) + (s + 1) * FDIM))[d];
        }

        // speculative poll issue (flies under early dots)
        unsigned long long pv = 0;
        unsigned long long* src = nullptr;
        const bool gathering = (s > 0 && gt >= 0 && gt < 192);
        if (gathering) {
            int mi = gt >> 6;                  // partner m = mi+1 (0..2)
            int within = gt & 63;
            int r = within >> 5, dwj = within & 31;
            int cgp = (cg + mi + 1) & 3;
            src = &ex2[(((pg * 4 + cgp) * 2 + (s & 1)) * 2 + r) * 32 + dwj];
            pv = __hip_atomic_load(src, __ATOMIC_RELAXED,
                                   __HIP_MEMORY_SCOPE_AGENT);
        }

        float A0 = 0.f, A1 = 0.f, A2 = 0.f, A3 = 0.f;   // row 0
        float B0 = 0.f, B1_ = 0.f, B2 = 0.f, B3 = 0.f;  // row 1

        // early dots: words {kq, 4+kq, 8+kq, 12+kq} (k' 0..127 = x + own-h)
        #pragma unroll
        for (int i = 0; i < 4; ++i) {
            int w = i * 4 + kq;
            uint4 wv = ldsW[i * 1024 + slotbase];
            uint4 x0 = X0[w], x1 = X1[w];
            DOT4(A0, A1, A2, A3, x0, wv);
            DOT4(B0, B1_, B2, B3, x1, wv);
        }

        // gather completion AFTER early dots: B1 at max(D_early, RTT-rem)
        if (gathering) {
            int it = 0;
            while ((unsigned)(pv >> 32) != (unsigned)s && ++it < (1 << 22))
                pv = __hip_atomic_load(src, __ATOMIC_RELAXED,
                                       __HIP_MEMORY_SCOPE_AGENT);
            unsigned gdw = ((unsigned)(pv >> 32) == (unsigned)s) ? (unsigned)pv : 0u;
            int mi = gt >> 6;
            int within = gt & 63;
            int r = within >> 5, dwj = within & 31;
            xh[cp][r][64 + mi * 32 + dwj] = gdw;
        }
        __syncthreads();                       // B1: partner xh in place

        // late dots: LDS words {16+kq, 20+kq, 24+kq} + pinned {28+kq, 32+kq}
        //            + streamed {36+kq}   (partner-h region)
        #pragma unroll
        for (int i = 4; i < 7; ++i) {
            int w = i * 4 + kq;
            uint4 wv = ldsW[i * 1024 + slotbase];
            uint4 x0 = X0[w], x1 = X1[w];
            DOT4(A0, A1, A2, A3, x0, wv);
            DOT4(B0, B1_, B2, B3, x1, wv);
        }
        {
            uint4 x0 = X0[28 + kq], x1 = X1[28 + kq];
            DOT4(A0, A1, A2, A3, x0, Wp7);
            DOT4(B0, B1_, B2, B3, x1, Wp7);
        }
        {
            uint4 x0 = X0[32 + kq], x1 = X1[32 + kq];
            DOT4(A0, A1, A2, A3, x0, Wp8);
            DOT4(B0, B1_, B2, B3, x1, Wp8);
        }
        {
            uint4 x0 = X0[36 + kq], x1 = X1[36 + kq];
            DOT4(A0, A1, A2, A3, x0, sv);
            DOT4(B0, B1_, B2, B3, x1, sv);
        }
        float pA = (A0 + A1) + (A2 + A3);
        float pB = (B0 + B1_) + (B2 + B3);
        float tA = pA + __shfl_xor(pA, 16);
        float tB = pB + __shfl_xor(pB, 16);
        float fA = tA + __shfl_xor(tA, 32);
        float fB = tB + __shfl_xor(tB, 32);
        if ((tid & 48) == 0) {                 // kq==0 lanes (16 per wave)
            zs[0][col] = fA;
            zs[1][col] = fB;
        }
        __syncthreads();                       // B2: zs ready

        // ---- gates (waves 0,1) + own-h + tagged publish ----
        if (tid < 128) {
            const float zi = zs[grow][gj]       + bi;
            const float zf = zs[grow][64 + gj]  + bf;
            const float zc = zs[grow][128 + gj] + bc;
            const float zo = zs[grow][192 + gj] + bo;
            const float ig = 1.0f / (1.0f + __expf(-zi));
            const float fg = 1.0f / (1.0f + __expf(-zf));
            const float gg = 1.0f - 2.0f / (__expf(2.0f * zc) + 1.0f);
            const float og = 1.0f / (1.0f + __expf(-zo));
            cstate = fmaf(fg, cstate, ig * gg);
            const float hn = og * (1.0f - 2.0f / (__expf(2.0f * cstate) + 1.0f));
            const float hno = __shfl_xor(hn, 1);
            if (s == TSTEPS - 1) {
                out[(2 * pg + grow) * HDIM + cg * 64 + gj] =
                    (hn >= 0.0f) ? hn : 0.3f * hn;
            } else {
                ((_Float16*)&xh[ncp][grow][0])[64 + gj] = (_Float16)hn;
                if ((gj & 1) == 0) {
                    unsigned u = pack2(hn, hno);
                    unsigned long long pvw =
                        ((unsigned long long)(unsigned)(s + 1) << 32) |
                        (unsigned long long)u;
                    unsigned long long* dst =
                        &ex2[(((pg * 4 + cg) * 2 + ((s + 1) & 1)) * 2 + grow) * 32 + (gj >> 1)];
                    __hip_atomic_store(dst, pvw, __ATOMIC_RELAXED,
                                       __HIP_MEMORY_SCOPE_AGENT);
                }
            }
        } else if (tid >= 320 && tid < 384 && s + 1 < TSTEPS) {
            int t2 = tid - 320, r = t2 >> 5, d = t2 & 31;
            xh[ncp][r][d] = pack2(xnext.x, xnext.y);
        }
        __syncthreads();                       // B3: xh[ncp] consistent
    }
}

// ---- fallback (needs no ws): round-1 kernel ----
__global__ __launch_bounds__(HDIM) void lstm_fused(
    const float* __restrict__ inputs, const float* __restrict__ wk,
    const float* __restrict__ wr, const float* __restrict__ bias,
    float* __restrict__ out)
{
    const int b = blockIdx.x;
    const int t = threadIdx.x;
    __shared__ float hs[2][HDIM];
    __shared__ float xs[2][FDIM];
    const float* __restrict__ xin = inputs + (size_t)b * TSTEPS * FDIM;
    float c = 0.0f;
    hs[0][t] = 0.0f;
    if (t < FDIM) xs[0][t] = xin[t];
    const float bi = bias[t];
    const float bf = bias[HDIM + t];
    const float bc = bias[2 * HDIM + t];
    const float bo = bias[3 * HDIM + t];
    __syncthreads();
    int p = 0;
    for (int step = 0; step < TSTEPS; ++step) {
        float zi = bi, zf = bf, zc = bc, zo = bo;
        const float* xsp = xs[p];
        const float* hsp = hs[p];
        #pragma unroll 8
        for (int f = 0; f < FDIM; ++f) {
            const float xv = xsp[f];
            const float* Kf = wk + f * G4 + t;
            zi = fmaf(xv, Kf[0], zi);
            zf = fmaf(xv, Kf[HDIM], zf);
            zc = fmaf(xv, Kf[2 * HDIM], zc);
            zo = fmaf(xv, Kf[3 * HDIM], zo);
        }
        #pragma unroll 8
        for (int k = 0; k < HDIM; ++k) {
            const float hv = hsp[k];
            const float* Rk = wr + k * G4 + t;
            zi = fmaf(hv, Rk[0], zi);
            zf = fmaf(hv, Rk[HDIM], zf);
            zc = fmaf(hv, Rk[2 * HDIM], zc);
            zo = fmaf(hv, Rk[3 * HDIM], zo);
        }
        const float ig = 1.0f / (1.0f + __expf(-zi));
        const float fg = 1.0f / (1.0f + __expf(-zf));
        const float gg = 1.0f - 2.0f / (__expf(2.0f * zc) + 1.0f);
        const float og = 1.0f / (1.0f + __expf(-zo));
        c = fmaf(fg, c, ig * gg);
        const float hn = og * (1.0f - 2.0f / (__expf(2.0f * c) + 1.0f));
        float xnext = 0.0f;
        if (t < FDIM && step + 1 < TSTEPS) xnext = xin[(step + 1) * FDIM + t];
        hs[p ^ 1][t] = hn;
        if (t < FDIM) xs[p ^ 1][t] = xnext;
        __syncthreads();
        p ^= 1;
    }
    const float h = hs[p][t];
    out[b * HDIM + t] = (h >= 0.0f) ? h : 0.3f * h;
}

extern "C" void kernel_launch(void* const* d_in, const int* in_sizes, int n_in,
                              void* d_out, int out_size, void* d_ws, size_t ws_size,
                              hipStream_t stream) {
    const float* inputs = (const float*)d_in[0];
    const float* wk     = (const float*)d_in[1];
    const float* wr     = (const float*)d_in[2];
    const float* bias   = (const float*)d_in[3];
    float* out          = (float*)d_out;

    if (ws_size >= (size_t)WS_NEED) {
        unsigned* w4s = (unsigned*)d_ws;
        unsigned long long* ex2 = (unsigned long long*)((char*)d_ws + EX_OFF);
        hipMemsetAsync(ex2, 0xFF, EX_BYTES, stream);   // all tags invalid
        int ndw = W4S_U4 * 4;
        pack_weights4<<<dim3((ndw + 255) / 256), dim3(256), 0, stream>>>(wk, wr, w4s);
        lstm_4way<<<dim3(256), dim3(1024), 0, stream>>>(
            inputs, (const uint4*)w4s, bias, ex2, out);
    } else {
        lstm_fused<<<dim3(BATCH), dim3(HDIM), 0, stream>>>(inputs, wk, wr, bias, out);
    }
}